// Round 1
// baseline (433.923 us; speedup 1.0000x reference)
//
#include <hip/hip_runtime.h>

#define HW 128
#define CC 64
#define OO 64
#define BB 4

// ws layout (floats):
//   wt    [0, 36864)            wt[(t*64+c)*64 + o] = w[o][c][t]
//   wofft [36864, 47232)        wofft[(c*9+kh*3+kw)*18 + oc] = w_off[oc][c][kh][kw]
//   dy    [47232, 637056)       dy[((b*9+t)*128+h)*128 + w]
//   dx    [637056, 1226880)
// total 1,226,880 floats = 4.9 MB

__global__ __launch_bounds__(256) void k_prep(const float* __restrict__ w,
                                              const float* __restrict__ w_off,
                                              float* __restrict__ wt,
                                              float* __restrict__ wofft) {
  int i = blockIdx.x * 256 + threadIdx.x;
  if (i < 576 * 64) {
    int o = i & 63, tc = i >> 6;
    int c = tc & 63, t = tc >> 6;
    wt[i] = w[o * 576 + c * 9 + t];
  }
  if (i < 576 * 18) {
    int oc = i % 18, ck = i / 18;
    wofft[i] = w_off[oc * 576 + ck];
  }
}

__global__ __launch_bounds__(256) void k_off(const float* __restrict__ x,
                                             const float* __restrict__ wofft,
                                             const float* __restrict__ b_off,
                                             float* __restrict__ dyA,
                                             float* __restrict__ dxA) {
  int p = blockIdx.x * 256 + threadIdx.x;      // pixel id
  int w = p & 127, h = (p >> 7) & 127, b = p >> 14;
  float acc[18];
#pragma unroll
  for (int oc = 0; oc < 18; ++oc) acc[oc] = b_off[oc];
  const float* xb = x + b * (CC * HW * HW);
  for (int c = 0; c < CC; ++c) {
    const float* xc = xb + c * (HW * HW);
#pragma unroll
    for (int kh = 0; kh < 3; ++kh) {
      int y = h + kh - 1;
      bool yok = ((unsigned)y < HW);
#pragma unroll
      for (int kw = 0; kw < 3; ++kw) {
        int xx = w + kw - 1;
        bool ok = yok && ((unsigned)xx < HW);
        float xv = ok ? xc[y * HW + xx] : 0.0f;
        const float* wp = wofft + ((c * 3 + kh) * 3 + kw) * 18;  // wave-uniform -> s_load
#pragma unroll
        for (int oc = 0; oc < 18; ++oc) acc[oc] = fmaf(xv, wp[oc], acc[oc]);
      }
    }
  }
#pragma unroll
  for (int t = 0; t < 9; ++t) {
    int base = ((b * 9 + t) * HW + h) * HW + w;
    dyA[base] = acc[2 * t];
    dxA[base] = acc[2 * t + 1];
  }
}

__global__ __launch_bounds__(256) void k_main(const float* __restrict__ x,
                                              const float* __restrict__ wt,
                                              const float* __restrict__ dyA,
                                              const float* __restrict__ dxA,
                                              const float* __restrict__ bias,
                                              float* __restrict__ out) {
  __shared__ __align__(16) float samp[64 * 128];  // [c within chunk][pixel]
  int blk = blockIdx.x;              // b*128 + h
  int h = blk & 127, b = blk >> 7;
  int tid = threadIdx.x;
  const float* xb = x + b * (CC * HW * HW);

  // phase-2 mapping: thread computes 8 o's x 4 pixels
  int ot = tid & 7;                  // o = ot*8 + q
  int pg = tid >> 3;                 // pixels pg*4 .. pg*4+3
  float acc[8][4];
#pragma unroll
  for (int q = 0; q < 8; ++q)
#pragma unroll
    for (int j = 0; j < 4; ++j) acc[q][j] = 0.0f;

  // phase-1 mapping: thread samples pixel `pix`, channels c = 2k + hi
  int pix = tid & 127;
  int hi = tid >> 7;

  for (int t = 0; t < 9; ++t) {
    // --- geometry for (pixel, tap t): computed once per chunk ---
    int base = ((b * 9 + t) * HW + h) * HW + pix;
    float py = (float)(h + (t / 3) - 1) + dyA[base];
    float px = (float)(pix + (t % 3) - 1) + dxA[base];
    float y0f = floorf(py), x0f = floorf(px);
    float wy = py - y0f, wx = px - x0f;
    int y0 = (int)y0f, x0 = (int)x0f;
    int y1 = y0 + 1, x1 = x0 + 1;
    // fold validity into lerp weights; clamp addresses (always-safe loads)
    float f00 = (((unsigned)y0 < HW) && ((unsigned)x0 < HW)) ? (1.0f - wy) * (1.0f - wx) : 0.0f;
    float f01 = (((unsigned)y0 < HW) && ((unsigned)x1 < HW)) ? (1.0f - wy) * wx : 0.0f;
    float f10 = (((unsigned)y1 < HW) && ((unsigned)x0 < HW)) ? wy * (1.0f - wx) : 0.0f;
    float f11 = (((unsigned)y1 < HW) && ((unsigned)x1 < HW)) ? wy * wx : 0.0f;
    int y0c = min(max(y0, 0), HW - 1), y1c = min(max(y1, 0), HW - 1);
    int x0c = min(max(x0, 0), HW - 1), x1c = min(max(x1, 0), HW - 1);
    int a00 = y0c * HW + x0c, a01 = y0c * HW + x1c;
    int a10 = y1c * HW + x0c, a11 = y1c * HW + x1c;

    __syncthreads();  // previous chunk's phase-2 reads are done
    // --- phase 1: sample this tap for 64 channels (this thread: 32 of them) ---
    for (int k = 0; k < 32; ++k) {
      int c = 2 * k + hi;
      const float* xc = xb + c * (HW * HW);
      float v00 = xc[a00], v01 = xc[a01], v10 = xc[a10], v11 = xc[a11];
      samp[c * 128 + pix] = fmaf(v00, f00, fmaf(v01, f01, fmaf(v10, f10, v11 * f11)));
    }
    __syncthreads();

    // --- phase 2: accumulate this chunk's 64 K-steps ---
    const float* wrow = wt + t * (64 * 64);
    for (int ci = 0; ci < 64; ++ci) {
      float4 s4 = *reinterpret_cast<const float4*>(&samp[ci * 128 + pg * 4]);
      float4 wa = *reinterpret_cast<const float4*>(&wrow[ci * 64 + ot * 8]);
      float4 wb = *reinterpret_cast<const float4*>(&wrow[ci * 64 + ot * 8 + 4]);
      float wq[8] = {wa.x, wa.y, wa.z, wa.w, wb.x, wb.y, wb.z, wb.w};
#pragma unroll
      for (int q = 0; q < 8; ++q) {
        acc[q][0] = fmaf(wq[q], s4.x, acc[q][0]);
        acc[q][1] = fmaf(wq[q], s4.y, acc[q][1]);
        acc[q][2] = fmaf(wq[q], s4.z, acc[q][2]);
        acc[q][3] = fmaf(wq[q], s4.w, acc[q][3]);
      }
    }
  }

  // --- epilogue: bias + store ---
#pragma unroll
  for (int q = 0; q < 8; ++q) {
    int o = ot * 8 + q;
    float bz = bias[o];
    float4 r;
    r.x = acc[q][0] + bz; r.y = acc[q][1] + bz;
    r.z = acc[q][2] + bz; r.w = acc[q][3] + bz;
    *reinterpret_cast<float4*>(&out[((b * OO + o) * HW + h) * HW + pg * 4]) = r;
  }
}

extern "C" void kernel_launch(void* const* d_in, const int* in_sizes, int n_in,
                              void* d_out, int out_size, void* d_ws, size_t ws_size,
                              hipStream_t stream) {
  const float* x     = (const float*)d_in[0];
  const float* w_off = (const float*)d_in[1];
  const float* b_off = (const float*)d_in[2];
  const float* w     = (const float*)d_in[3];
  const float* bias  = (const float*)d_in[4];
  float* out = (float*)d_out;
  float* ws  = (float*)d_ws;

  float* wt    = ws;
  float* wofft = ws + 36864;
  float* dy    = ws + 47232;
  float* dx    = dy + 589824;

  hipLaunchKernelGGL(k_prep, dim3(144), dim3(256), 0, stream, w, w_off, wt, wofft);
  hipLaunchKernelGGL(k_off,  dim3(256), dim3(256), 0, stream, x, wofft, b_off, dy, dx);
  hipLaunchKernelGGL(k_main, dim3(512), dim3(256), 0, stream, x, wt, dy, dx, bias, out);
}

// Round 2
// 402.641 us; speedup vs baseline: 1.0777x; 1.0777x over previous
//
#include <hip/hip_runtime.h>
#include <hip/hip_bf16.h>

#define HW 128

// ws layout (floats):
//   wt    [0, 36864)       wt[(t*64+c)*64 + o]        = w[o][c][t]
//   wofft [36864, 47232)   wofft[((pos*18)+oc)*64 + c] = w_off[oc][c][pos]
//   xt    [47232, +4.19M bf16)  xt[((b*128+h)*128+w)*64 + c]  (bf16)
// total ~8.6 MB

__device__ __forceinline__ unsigned short f2bf(float v) {
  __hip_bfloat16 h = __float2bfloat16(v);
  return *reinterpret_cast<unsigned short*>(&h);
}

__device__ __forceinline__ void bf8_to_f32(const int4& r, float* f) {
  const unsigned int* u = reinterpret_cast<const unsigned int*>(&r);
#pragma unroll
  for (int k = 0; k < 4; ++k) {
    f[2 * k]     = __uint_as_float(u[k] << 16);
    f[2 * k + 1] = __uint_as_float(u[k] & 0xffff0000u);
  }
}

__global__ __launch_bounds__(256) void k_prep(const float* __restrict__ w,
                                              const float* __restrict__ w_off,
                                              float* __restrict__ wt,
                                              float* __restrict__ wofft) {
  int i = blockIdx.x * 256 + threadIdx.x;
  if (i < 576 * 64) {
    int o = i & 63, tc = i >> 6;          // tc = t*64 + c
    int c = tc & 63, t = tc >> 6;
    wt[i] = w[o * 576 + c * 9 + t];
  }
  if (i < 9 * 18 * 64) {
    int c = i & 63, rem = i >> 6;         // rem = pos*18 + oc
    int oc = rem % 18, pos = rem / 18;
    wofft[i] = w_off[oc * 576 + c * 9 + pos];
  }
}

// x[b][c][h][w] f32  ->  xt[b][h][w][c] bf16
__global__ __launch_bounds__(256) void k_tr(const float* __restrict__ x,
                                            unsigned int* __restrict__ xt_u32) {
  __shared__ float tile[64 * 129];
  int blk = blockIdx.x;                   // b*128 + h
  int h = blk & 127, b = blk >> 7;
  int tid = threadIdx.x;
  int w0 = tid & 127, ch = tid >> 7;      // ch in {0,1}
  const float* xb = x + ((size_t)b * 64 * HW + h) * HW;   // x[b][0][h][0]
#pragma unroll
  for (int k = 0; k < 32; ++k) {
    int c = ch * 32 + k;
    float v = xb[c * (HW * HW) + w0];
    tile[c * 129 + (w0 ^ (c & 1))] = v;   // xor keeps read phase conflict-free
  }
  __syncthreads();
  int c2 = tid & 31, wg = tid >> 5;
#pragma unroll
  for (int k = 0; k < 16; ++k) {
    int ww = wg * 16 + k;
    float lo = tile[(2 * c2) * 129 + ww];
    float hi = tile[(2 * c2 + 1) * 129 + (ww ^ 1)];
    unsigned int packed = (unsigned int)f2bf(lo) | ((unsigned int)f2bf(hi) << 16);
    xt_u32[((b * HW + h) * HW + ww) * 32 + c2] = packed;
  }
}

// one block = 32 pixels of one row; phases: A offsets-conv -> per tap {gather, GEMM}
__global__ __launch_bounds__(256, 6) void k_main(const unsigned short* __restrict__ xt,
                                                 const float* __restrict__ wt,
                                                 const float* __restrict__ wofft,
                                                 const float* __restrict__ b_off,
                                                 const float* __restrict__ bias,
                                                 float* __restrict__ out) {
  __shared__ float samp[32 * 68];   // [pixel][64c + pad], slot-swizzled
  __shared__ float offs[32 * 20];   // [pixel][18 oc + pad]

  int bid = blockIdx.x;
  bid = (bid & 7) * 256 + (bid >> 3);           // XCD swizzle (2048 % 8 == 0)
  int qw = bid & 3, h = (bid >> 2) & 127, b = bid >> 9;
  int tid = threadIdx.x;
  int g = tid & 7, p = tid >> 3;                // g: c-chunk / o-chunk, p: pixel 0..31
  int psw = p & 7;
  int wx = qw * 32 + p;

  // ---- Phase A: offsets conv (thread: channels g*8..+7 of pixel p) ----
  float acc18[18];
#pragma unroll
  for (int oc = 0; oc < 18; ++oc) acc18[oc] = 0.f;

  for (int pos = 0; pos < 9; ++pos) {
    int kh = pos / 3, kw = pos % 3;
    int y = h + kh - 1, xx = wx + kw - 1;
    bool ok = ((unsigned)y < HW) && ((unsigned)xx < HW);
    int4 raw = make_int4(0, 0, 0, 0);
    if (ok) raw = *reinterpret_cast<const int4*>(xt + (((b * HW + y) * HW + xx) * 64 + g * 8));
    float xv[8];
    bf8_to_f32(raw, xv);
    const float* wr = wofft + pos * 18 * 64 + g * 8;
#pragma unroll
    for (int oc = 0; oc < 18; ++oc) {
      float4 wa = *reinterpret_cast<const float4*>(wr + oc * 64);
      float4 wb = *reinterpret_cast<const float4*>(wr + oc * 64 + 4);
      float s = acc18[oc];
      s = fmaf(xv[0], wa.x, s); s = fmaf(xv[1], wa.y, s);
      s = fmaf(xv[2], wa.z, s); s = fmaf(xv[3], wa.w, s);
      s = fmaf(xv[4], wb.x, s); s = fmaf(xv[5], wb.y, s);
      s = fmaf(xv[6], wb.z, s); s = fmaf(xv[7], wb.w, s);
      acc18[oc] = s;
    }
  }
#pragma unroll
  for (int oc = 0; oc < 18; ++oc) {       // butterfly over the 8 c-chunk lanes
    float v = acc18[oc];
    v += __shfl_xor(v, 1);
    v += __shfl_xor(v, 2);
    v += __shfl_xor(v, 4);
    acc18[oc] = v;
  }
  offs[p * 20 + g]     = acc18[g]     + b_off[g];
  offs[p * 20 + 8 + g] = acc18[8 + g] + b_off[8 + g];
  if (g < 2) offs[p * 20 + 16 + g] = acc18[16 + g] + b_off[16 + g];
  __syncthreads();

  // ---- per-tap gather + fp32 GEMM ----
  float acc[8];
#pragma unroll
  for (int q = 0; q < 8; ++q) acc[q] = 0.f;

  const unsigned short* xtb = xt + (size_t)b * (HW * HW * 64) + g * 8;

  for (int t = 0; t < 9; ++t) {
    int ti = t / 3, tj = t % 3;
    float2 d = *reinterpret_cast<const float2*>(&offs[p * 20 + 2 * t]);
    float py = (float)(h + ti - 1) + d.x;
    float px = (float)(wx + tj - 1) + d.y;
    float y0f = floorf(py), x0f = floorf(px);
    float wy = py - y0f, wxf = px - x0f;
    int y0 = (int)y0f, x0 = (int)x0f;
    int y1 = y0 + 1, x1 = x0 + 1;
    float f00 = (((unsigned)y0 < HW) && ((unsigned)x0 < HW)) ? (1.f - wy) * (1.f - wxf) : 0.f;
    float f01 = (((unsigned)y0 < HW) && ((unsigned)x1 < HW)) ? (1.f - wy) * wxf : 0.f;
    float f10 = (((unsigned)y1 < HW) && ((unsigned)x0 < HW)) ? wy * (1.f - wxf) : 0.f;
    float f11 = (((unsigned)y1 < HW) && ((unsigned)x1 < HW)) ? wy * wxf : 0.f;
    int y0c = min(max(y0, 0), HW - 1), y1c = min(max(y1, 0), HW - 1);
    int x0c = min(max(x0, 0), HW - 1), x1c = min(max(x1, 0), HW - 1);
    int4 r00 = *reinterpret_cast<const int4*>(xtb + (y0c * HW + x0c) * 64);
    int4 r01 = *reinterpret_cast<const int4*>(xtb + (y0c * HW + x1c) * 64);
    int4 r10 = *reinterpret_cast<const int4*>(xtb + (y1c * HW + x0c) * 64);
    int4 r11 = *reinterpret_cast<const int4*>(xtb + (y1c * HW + x1c) * 64);
    float v00[8], v01[8], v10[8], v11[8];
    bf8_to_f32(r00, v00); bf8_to_f32(r01, v01);
    bf8_to_f32(r10, v10); bf8_to_f32(r11, v11);
    float s[8];
#pragma unroll
    for (int j = 0; j < 8; ++j)
      s[j] = fmaf(v11[j], f11, fmaf(v10[j], f10, fmaf(v01[j], f01, v00[j] * f00)));

    __syncthreads();   // previous tap's GEMM reads done
    // slot scheme: logical f4-chunk cf -> phys slot rot(cf)^psw, rot(cf)=((cf&1)<<3)|(cf>>1)
    // thread's chunks are cf=2g (->slot g^psw) and cf=2g+1 (->slot 8+(g^psw)): starts cover all 32 banks
    float* dst = samp + p * 68 + ((g ^ psw) << 2);
    *reinterpret_cast<float4*>(dst)      = make_float4(s[0], s[1], s[2], s[3]);
    *reinterpret_cast<float4*>(dst + 32) = make_float4(s[4], s[5], s[6], s[7]);
    __syncthreads();   // samp ready

    const float* wrow = wt + t * 4096 + g * 8;   // this thread's 8 o's
    const float* srow = samp + p * 68;
#pragma unroll 2
    for (int ci4 = 0; ci4 < 16; ++ci4) {
      int slot = (((ci4 & 1) << 3) | (ci4 >> 1)) ^ psw;
      float4 s4 = *reinterpret_cast<const float4*>(srow + (slot << 2));
      const float* sv = reinterpret_cast<const float*>(&s4);
      const float* wp = wrow + ci4 * 256;
#pragma unroll
      for (int u = 0; u < 4; ++u) {
        float svu = sv[u];
        float4 wa = *reinterpret_cast<const float4*>(wp + u * 64);
        float4 wb = *reinterpret_cast<const float4*>(wp + u * 64 + 4);
        acc[0] = fmaf(svu, wa.x, acc[0]);
        acc[1] = fmaf(svu, wa.y, acc[1]);
        acc[2] = fmaf(svu, wa.z, acc[2]);
        acc[3] = fmaf(svu, wa.w, acc[3]);
        acc[4] = fmaf(svu, wb.x, acc[4]);
        acc[5] = fmaf(svu, wb.y, acc[5]);
        acc[6] = fmaf(svu, wb.z, acc[6]);
        acc[7] = fmaf(svu, wb.w, acc[7]);
      }
    }
  }

  // ---- epilogue ----
#pragma unroll
  for (int q = 0; q < 8; ++q) {
    int o = g * 8 + q;
    out[((b * 64 + o) * HW + h) * HW + wx] = acc[q] + bias[o];
  }
}

extern "C" void kernel_launch(void* const* d_in, const int* in_sizes, int n_in,
                              void* d_out, int out_size, void* d_ws, size_t ws_size,
                              hipStream_t stream) {
  const float* x     = (const float*)d_in[0];
  const float* w_off = (const float*)d_in[1];
  const float* b_off = (const float*)d_in[2];
  const float* w     = (const float*)d_in[3];
  const float* bias  = (const float*)d_in[4];
  float* out = (float*)d_out;
  float* ws  = (float*)d_ws;

  float* wt    = ws;
  float* wofft = ws + 36864;
  unsigned short* xt = (unsigned short*)(ws + 47232);   // 16B-aligned (47232*4 % 16 == 0)

  hipLaunchKernelGGL(k_prep, dim3(144), dim3(256), 0, stream, w, w_off, wt, wofft);
  hipLaunchKernelGGL(k_tr,   dim3(512), dim3(256), 0, stream, x, (unsigned int*)xt);
  hipLaunchKernelGGL(k_main, dim3(2048), dim3(256), 0, stream, xt, wt, wofft, b_off, bias, out);
}